// Round 9
// baseline (153.155 us; speedup 1.0000x reference)
//
#include <hip/hip_runtime.h>

#define B_DIM 4096
#define L_DIM 4096
#define SEGLEN 128
#define NSEG (L_DIM / SEGLEN)   // 32
#define WARM 384                // delta <= 25*0.95^384 = 6.7e-8 < ulp(1.0); segs 0..3 exact
#define CHUNK 16                // time steps per LDS chunk
#define RPB 256                 // rows per block (4 per lane -> ILP x4 fills dep latency)

typedef float f4 __attribute__((ext_vector_type(4)));

// ws: float C_acc[4096], float ts_acc[4096], int first_acc[4096]
__global__ __launch_bounds__(256) void init_kernel(float* wsf, int* wsi) {
    int i = blockIdx.x * 256 + threadIdx.x;
    if (i < 2 * B_DIM) wsf[i] = 0.f;
    if (i < B_DIM) wsi[i] = L_DIM;
}

__device__ __forceinline__ void dma16(const float* g, float* l) {
    __builtin_amdgcn_global_load_lds(
        (const __attribute__((address_space(1))) unsigned int*)g,
        (__attribute__((address_space(3))) unsigned int*)l, 16, 0, 0);
}

// Exact IEEE step (proven absmax 0 in r5-r8): q = RN(u/20) via Markstein,
// compare off the carried chain: u' = sp_prev ? I' : ((u-q)+I')
#define CORE(N, IIN)                                              \
    { float q0 = u##N * cdiv; float rr = fmaf(-20.0f, q0, u##N);  \
      float q = fmaf(rr, cdiv, q0); float a = u##N - q;           \
      float b = a + (IIN); u##N = sp##N ? (IIN) : b;              \
      sp##N = (u##N >= 1.0f); }

#define FULL(N, IIN, SOUT)                                        \
    { CORE(N, IIN)                                                \
      float sf = sp##N ? 1.0f : 0.0f; cnt##N += sf;               \
      seen##N = fmaxf(seen##N, sf); accS##N += cnt##N;            \
      accF##N += seen##N; (SOUT) = sf; }

// Single wave per block; 4 chains per lane (rows lane, lane+64, +128, +192).
// Chunked: DMA(c+1) fire-and-forget at top, s_waitcnt vmcnt(N) gates chunk c's
// ds_reads without ever draining the scattered spike stores.
// LDS granule swizzle: granule(row r, f4-group g) = r*4 + (g ^ (r&3))
//   - producer lane(p,l): G = p*64+l (wave-uniform+lane*16, DMA-legal)
//   - consumer b128 banks spread 16x16 (2-way aliasing = free per m136)
__global__ __launch_bounds__(64, 1) void lif_kernel(const float* __restrict__ I,
                                                    float* __restrict__ out,
                                                    float* __restrict__ Cacc,
                                                    float* __restrict__ tsAcc,
                                                    int* __restrict__ firstAcc) {
    __shared__ __align__(16) float lds[2][RPB * CHUNK];  // 2 x 16 KB
    const int lane = threadIdx.x;
    const int grp = blockIdx.x & 15;   // 16 row groups
    const int seg = blockIdx.x >> 4;   // 32 segments
    const int rowBase = grp * RPB;
    const int t0 = seg * SEGLEN;
    const int start = (t0 >= WARM) ? (t0 - WARM) : 0;
    const int warmSteps = t0 - start;            // 0..384, multiple of CHUNK
    const int nwarmCh = warmSteps / CHUNK;
    const int nch = nwarmCh + SEGLEN / CHUNK;    // 8..32

    // producer lane constants: instr p, lane -> row p*16+(lane>>2), group (lane&3)^((lane>>2)&3)
    const float* psrc = I + (size_t)(rowBase + (lane >> 2)) * L_DIM + start +
                        (((lane & 3) ^ ((lane >> 2) & 3)) << 2);

#define DMA_CHUNK(BUFI, CC)                                           \
    {                                                                 \
        float* ldst = &lds[BUFI][0] + (lane << 2);                    \
        const float* gsrc = psrc + (size_t)(CC) * CHUNK;              \
        _Pragma("unroll")                                             \
        for (int p = 0; p < 16; ++p)                                  \
            dma16(gsrc + (size_t)(p * 16) * L_DIM, ldst + p * 256);   \
    }

    // chain state
    float u0 = 0.f, cnt0 = 0.f, seen0 = 0.f, accS0 = 0.f, accF0 = 0.f;
    float u1 = 0.f, cnt1 = 0.f, seen1 = 0.f, accS1 = 0.f, accF1 = 0.f;
    float u2 = 0.f, cnt2 = 0.f, seen2 = 0.f, accS2 = 0.f, accF2 = 0.f;
    float u3 = 0.f, cnt3 = 0.f, seen3 = 0.f, accS3 = 0.f, accF3 = 0.f;
    bool sp0 = false, sp1 = false, sp2 = false, sp3 = false;
    const float cdiv = 0.05f;  // RN(1/20)

    const int row0 = rowBase + lane, row1 = row0 + 64, row2 = row0 + 128, row3 = row0 + 192;
    float* so0 = out + (size_t)row0 * L_DIM + t0;
    float* so1 = out + (size_t)row1 * L_DIM + t0;
    float* so2 = out + (size_t)row2 * L_DIM + t0;
    float* so3 = out + (size_t)row3 * L_DIM + t0;

    const int lbase = lane << 4;   // lane*16 floats
    const int rot = lane & 3;

    DMA_CHUNK(0, 0)
    for (int c = 0; c < nch; ++c) {
        if (c + 1 < nch) DMA_CHUNK((c + 1) & 1, c + 1)
        // queue (in order): [DMA(c) x16, stores(c-1) x16, DMA(c+1) x16]
        if (c == 0 || c == nch - 1)
            asm volatile("s_waitcnt vmcnt(16)" ::: "memory");
        else
            asm volatile("s_waitcnt vmcnt(32)" ::: "memory");

        const float* buf = &lds[c & 1][0];
        // 16 granule reads (chain j at +j*1024, group g at ((g^rot)<<2))
        f4 v00 = *(const f4*)(buf + lbase + ((0 ^ rot) << 2));
        f4 v01 = *(const f4*)(buf + lbase + ((1 ^ rot) << 2));
        f4 v02 = *(const f4*)(buf + lbase + ((2 ^ rot) << 2));
        f4 v03 = *(const f4*)(buf + lbase + ((3 ^ rot) << 2));
        f4 v10 = *(const f4*)(buf + 1024 + lbase + ((0 ^ rot) << 2));
        f4 v11 = *(const f4*)(buf + 1024 + lbase + ((1 ^ rot) << 2));
        f4 v12 = *(const f4*)(buf + 1024 + lbase + ((2 ^ rot) << 2));
        f4 v13 = *(const f4*)(buf + 1024 + lbase + ((3 ^ rot) << 2));
        f4 v20 = *(const f4*)(buf + 2048 + lbase + ((0 ^ rot) << 2));
        f4 v21 = *(const f4*)(buf + 2048 + lbase + ((1 ^ rot) << 2));
        f4 v22 = *(const f4*)(buf + 2048 + lbase + ((2 ^ rot) << 2));
        f4 v23 = *(const f4*)(buf + 2048 + lbase + ((3 ^ rot) << 2));
        f4 v30 = *(const f4*)(buf + 3072 + lbase + ((0 ^ rot) << 2));
        f4 v31 = *(const f4*)(buf + 3072 + lbase + ((1 ^ rot) << 2));
        f4 v32 = *(const f4*)(buf + 3072 + lbase + ((2 ^ rot) << 2));
        f4 v33 = *(const f4*)(buf + 3072 + lbase + ((3 ^ rot) << 2));
        asm volatile("" : "+v"(v00), "+v"(v01), "+v"(v02), "+v"(v03),
                         "+v"(v10), "+v"(v11), "+v"(v12), "+v"(v13),
                         "+v"(v20), "+v"(v21), "+v"(v22), "+v"(v23),
                         "+v"(v30), "+v"(v31), "+v"(v32), "+v"(v33));

        if (c < nwarmCh) {
#define WG(A, B, C2, D)                                      \
            { CORE(0, A.x) CORE(1, B.x) CORE(2, C2.x) CORE(3, D.x)   \
              CORE(0, A.y) CORE(1, B.y) CORE(2, C2.y) CORE(3, D.y)   \
              CORE(0, A.z) CORE(1, B.z) CORE(2, C2.z) CORE(3, D.z)   \
              CORE(0, A.w) CORE(1, B.w) CORE(2, C2.w) CORE(3, D.w) }
            WG(v00, v10, v20, v30) WG(v01, v11, v21, v31)
            WG(v02, v12, v22, v32) WG(v03, v13, v23, v33)
#undef WG
        } else {
            const int co = (c - nwarmCh) * CHUNK;
#define FG(A, B, C2, D, G)                                            \
            { f4 s0, s1, s2, s3;                                      \
              FULL(0, A.x, s0.x) FULL(1, B.x, s1.x) FULL(2, C2.x, s2.x) FULL(3, D.x, s3.x) \
              FULL(0, A.y, s0.y) FULL(1, B.y, s1.y) FULL(2, C2.y, s2.y) FULL(3, D.y, s3.y) \
              FULL(0, A.z, s0.z) FULL(1, B.z, s1.z) FULL(2, C2.z, s2.z) FULL(3, D.z, s3.z) \
              FULL(0, A.w, s0.w) FULL(1, B.w, s1.w) FULL(2, C2.w, s2.w) FULL(3, D.w, s3.w) \
              *(f4*)(so0 + co + ((G) << 2)) = s0;                     \
              *(f4*)(so1 + co + ((G) << 2)) = s1;                     \
              *(f4*)(so2 + co + ((G) << 2)) = s2;                     \
              *(f4*)(so3 + co + ((G) << 2)) = s3; }
            FG(v00, v10, v20, v30, 0) FG(v01, v11, v21, v31, 1)
            FG(v02, v12, v22, v32, 2) FG(v03, v13, v23, v33, 3)
#undef FG
        }
    }

    // per-segment partials (exact integers < 2^24 -> float atomics exact)
#define TAIL(N, ROW)                                                          \
    { if (cnt##N > 0.f)                                                       \
          atomicMin(&firstAcc[ROW], t0 + (int)((float)SEGLEN - accF##N));     \
      atomicAdd(&Cacc[ROW], cnt##N);                                          \
      atomicAdd(&tsAcc[ROW], fmaf((float)(t0 + SEGLEN), cnt##N, -accS##N)); }
    TAIL(0, row0) TAIL(1, row1) TAIL(2, row2) TAIL(3, row3)
#undef TAIL
#undef DMA_CHUNK
}

__global__ __launch_bounds__(256) void fin_kernel(const float* __restrict__ Cacc,
                                                  const float* __restrict__ tsAcc,
                                                  const int* __restrict__ firstAcc,
                                                  float* __restrict__ out) {
    int r = blockIdx.x * 256 + threadIdx.x;
    if (r < B_DIM) {
        out[(size_t)B_DIM * L_DIM + r] = (float)firstAcc[r];
        out[(size_t)B_DIM * L_DIM + B_DIM + r] = tsAcc[r] / (Cacc[r] + 1e-6f);
    }
}

extern "C" void kernel_launch(void* const* d_in, const int* in_sizes, int n_in,
                              void* d_out, int out_size, void* d_ws, size_t ws_size,
                              hipStream_t stream) {
    const float* I = (const float*)d_in[0];
    float* out = (float*)d_out;
    float* wsf = (float*)d_ws;
    int* wsi = (int*)((float*)d_ws + 2 * B_DIM);
    (void)in_sizes; (void)n_in; (void)out_size; (void)ws_size;

    init_kernel<<<(2 * B_DIM + 255) / 256, 256, 0, stream>>>(wsf, wsi);
    lif_kernel<<<16 * NSEG, 64, 0, stream>>>(I, out, wsf, wsf + B_DIM, wsi);
    fin_kernel<<<(B_DIM + 255) / 256, 256, 0, stream>>>(wsf, wsf + B_DIM, wsi, out);
}